// Round 4
// baseline (364.754 us; speedup 1.0000x reference)
//
#include <hip/hip_runtime.h>

#define TOK 64
#define CDIM 192
#define NH 6
#define HD 32
#define THREADS 768
#define QSCALE 0.17677669529663687f  // 32^-0.5

// workspace layout (halfs): w_qkv16 [576*192] | w_proj16 [192*192] | bias frags [6*4*64*16]
#define WQ16_OFF 0
#define WP16_OFF 110592
#define BIAS_OFF 147456
#define WS_HALFS (147456 + 24576)
#define WS_BYTES (WS_HALFS * 2)

typedef _Float16 f16x8 __attribute__((ext_vector_type(8)));
typedef _Float16 f16x4 __attribute__((ext_vector_type(4)));
typedef float f32x4 __attribute__((ext_vector_type(4)));

__device__ __forceinline__ f16x8 ld8(const _Float16* p) {
  return *reinterpret_cast<const f16x8*>(p);
}

__device__ __forceinline__ f16x8 cvt8(const float* __restrict__ p) {
  float4 a = *reinterpret_cast<const float4*>(p);
  float4 c = *reinterpret_cast<const float4*>(p + 4);
  f16x8 r;
  r[0] = (_Float16)a.x; r[1] = (_Float16)a.y; r[2] = (_Float16)a.z; r[3] = (_Float16)a.w;
  r[4] = (_Float16)c.x; r[5] = (_Float16)c.y; r[6] = (_Float16)c.z; r[7] = (_Float16)c.w;
  return r;
}

// Prologue: fp16 weights + per-(head,row-tile) bias fragments (two f16x8 per lane).
__global__ void prep_ws(const float* __restrict__ wq, const float* __restrict__ wp,
                        const float* __restrict__ bt, _Float16* __restrict__ ws) {
  int i = blockIdx.x * 256 + threadIdx.x;
  if (i < 27648) {
    float4 v = reinterpret_cast<const float4*>(wq)[i];
    f16x4 h;
    h[0] = (_Float16)v.x; h[1] = (_Float16)v.y; h[2] = (_Float16)v.z; h[3] = (_Float16)v.w;
    *reinterpret_cast<f16x4*>(ws + WQ16_OFF + (size_t)i * 4) = h;
  } else if (i < 36864) {
    int j = i - 27648;
    float4 v = reinterpret_cast<const float4*>(wp)[j];
    f16x4 h;
    h[0] = (_Float16)v.x; h[1] = (_Float16)v.y; h[2] = (_Float16)v.z; h[3] = (_Float16)v.w;
    *reinterpret_cast<f16x4*>(ws + WP16_OFF + (size_t)j * 4) = h;
  } else if (i < 61440) {
    int j = i - 36864;            // ((h*4+it)*64 + lane)*16 + (jt*4+r)
    int hit = j >> 10;
    int l = (j >> 4) & 63;
    int s = j & 15;
    int h = hit >> 2, it = hit & 3;
    int ii = it * 16 + (l & 15);
    int jj = (s >> 2) * 16 + (l >> 4) * 4 + (s & 3);
    int rel = ((ii >> 3) - (jj >> 3) + 7) * 15 + ((ii & 7) - (jj & 7) + 7);
    ws[BIAS_OFF + j] = (_Float16)bt[rel * NH + h];
  }
}

// Fused window attention: 1 block = 1 window, 12 waves, 48 KB LDS -> 2 blocks/CU.
// Wave w -> head h = w>>1, column-half / row-half = w&1.
// Overlay chains (each region provably dead before its next tenant):
//   Xb (24 KB): x panels -> q panels -> v^T panels -> attn-out O panels
//   Cb (24 KB): k panels -> P slices (per-wave 2 KB)
// Panel layout: elem(row,k) at [(k>>3)*ROWS + row]*8 + (k&7): all MFMA
// fragment accesses are contiguous 16B ds_read_b128.
template <bool WS>
__global__ __launch_bounds__(THREADS, 6) void winattn(
    const float* __restrict__ x, const float* __restrict__ w_qkv,
    const float* __restrict__ b_qkv, const float* __restrict__ w_proj,
    const float* __restrict__ b_proj, const float* __restrict__ bias_table,
    const _Float16* __restrict__ ws, float* __restrict__ out) {
  __shared__ __align__(16) _Float16 Xb[12288];  // x -> q -> v^T -> O
  __shared__ __align__(16) _Float16 Cb[12288];  // k -> P
  __shared__ float bias_sm[225 * NH];           // fallback path only (DCE'd if WS)

  const int tid = threadIdx.x;
  const int w   = tid >> 6;   // 0..11
  const int l   = tid & 63;
  const int l15 = l & 15;
  const int lg  = l >> 4;
  const int b   = blockIdx.x;
  const int h   = w >> 1;     // head
  const int wh  = w & 1;      // half (dims in QKV, rows in attention)
  const f32x4 vzero = {0.f, 0.f, 0.f, 0.f};

  // ---------------- stage x (fp32 -> fp16 panels) ----------------
  const float* xg = x + (size_t)b * (TOK * CDIM);
#pragma unroll
  for (int i = tid; i < TOK * CDIM / 4; i += THREADS) {
    int n = i / (CDIM / 4);
    int c = (i % (CDIM / 4)) * 4;
    float4 v = reinterpret_cast<const float4*>(xg)[i];
    f16x4 h4;
    h4[0] = (_Float16)v.x; h4[1] = (_Float16)v.y;
    h4[2] = (_Float16)v.z; h4[3] = (_Float16)v.w;
    *reinterpret_cast<f16x4*>(&Xb[((c >> 3) * TOK + n) * 8 + (c & 7)]) = h4;
  }
  if constexpr (!WS) {
    for (int i = tid; i < 225 * NH; i += THREADS) bias_sm[i] = bias_table[i];
  }
  __syncthreads();  // b0

  // ------- QKV GEMM (64x576, K=192); wave w -> col sdl of q,k,v -------
  const int sdl = h * HD + wh * 16 + l15;  // out-dim within each part
  f32x4 acc[3][4];
#pragma unroll
  for (int p = 0; p < 3; ++p)
#pragma unroll
    for (int mt = 0; mt < 4; ++mt) acc[p][mt] = vzero;

#pragma unroll
  for (int ks = 0; ks < 6; ++ks) {
    f16x8 a[4];
#pragma unroll
    for (int mt = 0; mt < 4; ++mt)
      a[mt] = ld8(&Xb[((ks * 4 + lg) * TOK + mt * 16 + l15) * 8]);
#pragma unroll
    for (int p = 0; p < 3; ++p) {
      int row = p * CDIM + sdl;
      f16x8 bf;
      if constexpr (WS) bf = ld8(ws + WQ16_OFF + (size_t)row * CDIM + ks * 32 + lg * 8);
      else              bf = cvt8(w_qkv + (size_t)row * CDIM + ks * 32 + lg * 8);
#pragma unroll
      for (int mt = 0; mt < 4; ++mt)
        acc[p][mt] = __builtin_amdgcn_mfma_f32_16x16x32_f16(a[mt], bf, acc[p][mt], 0, 0, 0);
    }
  }
  __syncthreads();  // b1: x reads done -> Xb reusable

  // epilogue: q -> Xb (over x), k -> Cb; v stays in registers
  {
    const int hd = wh * 16 + l15;  // dim within head
    float bq0 = b_qkv[sdl], bq1 = b_qkv[CDIM + sdl];
#pragma unroll
    for (int mt = 0; mt < 4; ++mt)
#pragma unroll
      for (int r = 0; r < 4; ++r) {
        int n = mt * 16 + lg * 4 + r;
        Xb[h * 2048 + ((hd >> 3) * TOK + n) * 8 + (hd & 7)] =
            (_Float16)((acc[0][mt][r] + bq0) * QSCALE);
        Cb[h * 2048 + ((hd >> 3) * TOK + n) * 8 + (hd & 7)] =
            (_Float16)(acc[1][mt][r] + bq1);
      }
  }
  __syncthreads();  // b2: q,k visible

  // hoist q,k fragments (wave needs only its own head)
  f16x8 qf[2], kf[4];
#pragma unroll
  for (int ii = 0; ii < 2; ++ii) {
    int it = wh * 2 + ii;
    qf[ii] = ld8(&Xb[h * 2048 + (lg * TOK + it * 16 + l15) * 8]);
  }
#pragma unroll
  for (int jt = 0; jt < 4; ++jt)
    kf[jt] = ld8(&Cb[h * 2048 + (lg * TOK + jt * 16 + l15) * 8]);
  __syncthreads();  // b3: q,k dead

  // v^T -> Xb (over q region)
  {
    const int hd = wh * 16 + l15;
    float bq2 = b_qkv[2 * CDIM + sdl];
#pragma unroll
    for (int mt = 0; mt < 4; ++mt)
#pragma unroll
      for (int r = 0; r < 4; ++r) {
        int n = mt * 16 + lg * 4 + r;
        Xb[h * 2048 + ((n >> 3) * HD + hd) * 8 + (n & 7)] = (_Float16)(acc[2][mt][r] + bq2);
      }
  }
  __syncthreads();  // b4: v^T visible

  // hoist v fragments
  f16x8 vf[4];
#pragma unroll
  for (int z = 0; z < 4; ++z) {  // z = ks*2+nt
    int ks = z >> 1, nt = z & 1;
    vf[z] = ld8(&Xb[h * 2048 + ((ks * 4 + lg) * HD + nt * 16 + l15) * 8]);
  }
  __syncthreads();  // b5: v^T dead -> Xb free for O

  // ---------------- attention: 2 row-tiles per wave ----------------
  {
    _Float16* pbase = &Cb[w * 1024];  // 2 KB P slice (over k region)
#pragma unroll
    for (int ii = 0; ii < 2; ++ii) {
      const int it = wh * 2 + ii;
      f32x4 st[4];
#pragma unroll
      for (int jt = 0; jt < 4; ++jt)
        st[jt] = __builtin_amdgcn_mfma_f32_16x16x32_f16(kf[jt], qf[ii], vzero, 0, 0, 0);
      // bias: lane holds (i = it*16+l15, j = jt*16+lg*4+r)
      if constexpr (WS) {
        const _Float16* bw = ws + BIAS_OFF + ((h * 4 + it) * 64 + l) * 16;
        f16x8 b0 = ld8(bw), b1 = ld8(bw + 8);
#pragma unroll
        for (int jt = 0; jt < 4; ++jt)
#pragma unroll
          for (int r = 0; r < 4; ++r)
            st[jt][r] += (float)((jt < 2) ? b0[jt * 4 + r] : b1[(jt - 2) * 4 + r]);
      } else {
        int i = it * 16 + l15, yi = i >> 3, xi = i & 7;
#pragma unroll
        for (int jt = 0; jt < 4; ++jt)
#pragma unroll
          for (int r = 0; r < 4; ++r) {
            int j = jt * 16 + lg * 4 + r, yj = j >> 3, xj = j & 7;
            st[jt][r] += bias_sm[((yi - yj + 7) * 15 + (xi - xj + 7)) * NH + h];
          }
      }
      // softmax over row i: 16 in-lane + lanes differing in lg (xor 16,32)
      float m = st[0][0];
#pragma unroll
      for (int jt = 0; jt < 4; ++jt)
#pragma unroll
        for (int r = 0; r < 4; ++r) m = fmaxf(m, st[jt][r]);
      m = fmaxf(m, __shfl_xor(m, 16, 64));
      m = fmaxf(m, __shfl_xor(m, 32, 64));
      float e[4][4], sum = 0.f;
#pragma unroll
      for (int jt = 0; jt < 4; ++jt)
#pragma unroll
        for (int r = 0; r < 4; ++r) { e[jt][r] = __expf(st[jt][r] - m); sum += e[jt][r]; }
      sum += __shfl_xor(sum, 16, 64);
      sum += __shfl_xor(sum, 32, 64);
      float inv = 1.f / sum;
      // P slice write (packed f16x4), layout [j>>3][i16][j&7]
#pragma unroll
      for (int jt = 0; jt < 4; ++jt) {
        f16x4 pk;
#pragma unroll
        for (int r = 0; r < 4; ++r) pk[r] = (_Float16)(e[jt][r] * inv);
        *reinterpret_cast<f16x4*>(
            &pbase[((jt * 2 + (lg >> 1)) * 16 + l15) * 8 + (lg & 1) * 4]) = pk;
      }
      // PV: O[16x32] = P[16x64] @ V[64x32]
      f32x4 o[2] = {vzero, vzero};
#pragma unroll
      for (int ks = 0; ks < 2; ++ks) {
        f16x8 pf = ld8(&pbase[((ks * 4 + lg) * 16 + l15) * 8]);
#pragma unroll
        for (int nt = 0; nt < 2; ++nt)
          o[nt] = __builtin_amdgcn_mfma_f32_16x16x32_f16(pf, vf[ks * 2 + nt], o[nt], 0, 0, 0);
      }
      // O -> Xb flat panels [c>>3][i][c&7]
#pragma unroll
      for (int nt = 0; nt < 2; ++nt) {
        int c = h * HD + nt * 16 + l15;
#pragma unroll
        for (int r = 0; r < 4; ++r) {
          int i2 = it * 16 + lg * 4 + r;
          Xb[((c >> 3) * TOK + i2) * 8 + (c & 7)] = (_Float16)o[nt][r];
        }
      }
    }
  }
  __syncthreads();  // b6: O visible

  // ------- projection (64x192, K=192); wave w -> e-tile w -------
  {
    const int e = w * 16 + l15;
    f32x4 pacc[4];
#pragma unroll
    for (int mt = 0; mt < 4; ++mt) pacc[mt] = vzero;
#pragma unroll
    for (int ks = 0; ks < 6; ++ks) {
      f16x8 bf;
      if constexpr (WS) bf = ld8(ws + WP16_OFF + (size_t)e * CDIM + ks * 32 + lg * 8);
      else              bf = cvt8(w_proj + (size_t)e * CDIM + ks * 32 + lg * 8);
#pragma unroll
      for (int mt = 0; mt < 4; ++mt) {
        f16x8 a = ld8(&Xb[((ks * 4 + lg) * TOK + mt * 16 + l15) * 8]);
        pacc[mt] = __builtin_amdgcn_mfma_f32_16x16x32_f16(a, bf, pacc[mt], 0, 0, 0);
      }
    }
    float bp = b_proj[e];
#pragma unroll
    for (int mt = 0; mt < 4; ++mt)
#pragma unroll
      for (int r = 0; r < 4; ++r) {
        int n = mt * 16 + lg * 4 + r;
        out[((size_t)b * TOK + n) * CDIM + e] = pacc[mt][r] + bp;
      }
  }
}

extern "C" void kernel_launch(void* const* d_in, const int* in_sizes, int n_in,
                              void* d_out, int out_size, void* d_ws, size_t ws_size,
                              hipStream_t stream) {
  const float* x          = (const float*)d_in[0];
  const float* w_qkv      = (const float*)d_in[1];
  const float* b_qkv      = (const float*)d_in[2];
  const float* w_proj     = (const float*)d_in[3];
  const float* b_proj     = (const float*)d_in[4];
  const float* bias_table = (const float*)d_in[5];
  float* out = (float*)d_out;
  int B = in_sizes[0] / (TOK * CDIM);

  if (ws_size >= (size_t)WS_BYTES) {
    _Float16* ws = (_Float16*)d_ws;
    hipLaunchKernelGGL(prep_ws, dim3(240), dim3(256), 0, stream,
                       w_qkv, w_proj, bias_table, ws);
    hipLaunchKernelGGL(winattn<true>, dim3(B), dim3(THREADS), 0, stream,
                       x, w_qkv, b_qkv, w_proj, b_proj, bias_table, ws, out);
  } else {
    hipLaunchKernelGGL(winattn<false>, dim3(B), dim3(THREADS), 0, stream,
                       x, w_qkv, b_qkv, w_proj, b_proj, bias_table,
                       (const _Float16*)nullptr, out);
  }
}

// Round 5
// 294.107 us; speedup vs baseline: 1.2402x; 1.2402x over previous
//
#include <hip/hip_runtime.h>

#define TOK 64
#define CDIM 192
#define NH 6
#define HD 32
#define THREADS 768
#define QSCALE 0.17677669529663687f  // 32^-0.5

// workspace layout (halfs): w_qkv16 [576*192] | w_proj16 [192*192] | bias frags [6*4*64*16]
#define WQ16_OFF 0
#define WP16_OFF 110592
#define BIAS_OFF 147456
#define WS_HALFS (147456 + 24576)
#define WS_BYTES (WS_HALFS * 2)

typedef _Float16 f16x8 __attribute__((ext_vector_type(8)));
typedef _Float16 f16x4 __attribute__((ext_vector_type(4)));
typedef float f32x4 __attribute__((ext_vector_type(4)));

__device__ __forceinline__ f16x8 ld8(const _Float16* p) {
  return *reinterpret_cast<const f16x8*>(p);
}

__device__ __forceinline__ f16x8 cvt8(const float* __restrict__ p) {
  float4 a = *reinterpret_cast<const float4*>(p);
  float4 c = *reinterpret_cast<const float4*>(p + 4);
  f16x8 r;
  r[0] = (_Float16)a.x; r[1] = (_Float16)a.y; r[2] = (_Float16)a.z; r[3] = (_Float16)a.w;
  r[4] = (_Float16)c.x; r[5] = (_Float16)c.y; r[6] = (_Float16)c.z; r[7] = (_Float16)c.w;
  return r;
}

// Prologue: fp16 weights + per-(head,row-tile) bias fragments (two f16x8 per lane).
__global__ void prep_ws(const float* __restrict__ wq, const float* __restrict__ wp,
                        const float* __restrict__ bt, _Float16* __restrict__ ws) {
  int i = blockIdx.x * 256 + threadIdx.x;
  if (i < 27648) {
    float4 v = reinterpret_cast<const float4*>(wq)[i];
    f16x4 h;
    h[0] = (_Float16)v.x; h[1] = (_Float16)v.y; h[2] = (_Float16)v.z; h[3] = (_Float16)v.w;
    *reinterpret_cast<f16x4*>(ws + WQ16_OFF + (size_t)i * 4) = h;
  } else if (i < 36864) {
    int j = i - 27648;
    float4 v = reinterpret_cast<const float4*>(wp)[j];
    f16x4 h;
    h[0] = (_Float16)v.x; h[1] = (_Float16)v.y; h[2] = (_Float16)v.z; h[3] = (_Float16)v.w;
    *reinterpret_cast<f16x4*>(ws + WP16_OFF + (size_t)j * 4) = h;
  } else if (i < 61440) {
    int j = i - 36864;            // ((h*4+it)*64 + lane)*16 + (jt*4+r)
    int hit = j >> 10;
    int l = (j >> 4) & 63;
    int s = j & 15;
    int h = hit >> 2, it = hit & 3;
    int ii = it * 16 + (l & 15);
    int jj = (s >> 2) * 16 + (l >> 4) * 4 + (s & 3);
    int rel = ((ii >> 3) - (jj >> 3) + 7) * 15 + ((ii & 7) - (jj & 7) + 7);
    ws[BIAS_OFF + j] = (_Float16)bt[rel * NH + h];
  }
}

// Fused window attention: 1 block = 1 window, 12 waves, 48 KB LDS -> 2 blocks/CU
// (co-scheduling at 48 KB proven in round 4). Spill-free by serializing the
// q/k/v transposes through rotating 24 KB regions so at most one acc plane is
// live across a barrier:
//   R1: x -> v^T -> O      R2: k -> q -> P slices
// Peak VGPR pressure is the QKV K-loop (identical to the 84-reg round-2 loop).
// Panel layout: elem(row,k) at [(k>>3)*ROWS + row]*8 + (k&7): all MFMA
// fragment accesses are contiguous 16B ds_read_b128.
template <bool WS>
__global__ __launch_bounds__(THREADS, 6) void winattn(
    const float* __restrict__ x, const float* __restrict__ w_qkv,
    const float* __restrict__ b_qkv, const float* __restrict__ w_proj,
    const float* __restrict__ b_proj, const float* __restrict__ bias_table,
    const _Float16* __restrict__ ws, float* __restrict__ out) {
  __shared__ __align__(16) _Float16 R1[12288];  // x -> v^T -> O
  __shared__ __align__(16) _Float16 R2[12288];  // k -> q -> P

  const int tid = threadIdx.x;
  const int w   = tid >> 6;   // 0..11
  const int l   = tid & 63;
  const int l15 = l & 15;
  const int lg  = l >> 4;
  const int b   = blockIdx.x;
  const int h   = w >> 1;     // head
  const int wh  = w & 1;      // half (dims in QKV, rows in attention)
  const f32x4 vzero = {0.f, 0.f, 0.f, 0.f};

  // ---------------- stage x (fp32 -> fp16 panels) ----------------
  const float* xg = x + (size_t)b * (TOK * CDIM);
#pragma unroll
  for (int i = tid; i < TOK * CDIM / 4; i += THREADS) {
    int n = i / (CDIM / 4);
    int c = (i % (CDIM / 4)) * 4;
    float4 v = reinterpret_cast<const float4*>(xg)[i];
    f16x4 h4;
    h4[0] = (_Float16)v.x; h4[1] = (_Float16)v.y;
    h4[2] = (_Float16)v.z; h4[3] = (_Float16)v.w;
    *reinterpret_cast<f16x4*>(&R1[((c >> 3) * TOK + n) * 8 + (c & 7)]) = h4;
  }
  __syncthreads();  // b0

  // ------- QKV GEMM (64x576, K=192); wave w -> col sdl of q,k,v -------
  const int sdl = h * HD + wh * 16 + l15;  // out-dim within each part
  const int hd  = wh * 16 + l15;           // dim within head
  f32x4 acc[3][4];
#pragma unroll
  for (int p = 0; p < 3; ++p)
#pragma unroll
    for (int mt = 0; mt < 4; ++mt) acc[p][mt] = vzero;

#pragma unroll
  for (int ks = 0; ks < 6; ++ks) {
    f16x8 a[4];
#pragma unroll
    for (int mt = 0; mt < 4; ++mt)
      a[mt] = ld8(&R1[((ks * 4 + lg) * TOK + mt * 16 + l15) * 8]);
#pragma unroll
    for (int p = 0; p < 3; ++p) {
      int row = p * CDIM + sdl;
      f16x8 bf;
      if constexpr (WS) bf = ld8(ws + WQ16_OFF + (size_t)row * CDIM + ks * 32 + lg * 8);
      else              bf = cvt8(w_qkv + (size_t)row * CDIM + ks * 32 + lg * 8);
#pragma unroll
      for (int mt = 0; mt < 4; ++mt)
        acc[p][mt] = __builtin_amdgcn_mfma_f32_16x16x32_f16(a[mt], bf, acc[p][mt], 0, 0, 0);
    }
  }

  // k -> R2 (acc[1] dies here)
  {
    float bq1 = b_qkv[CDIM + sdl];
#pragma unroll
    for (int mt = 0; mt < 4; ++mt)
#pragma unroll
      for (int r = 0; r < 4; ++r) {
        int n = mt * 16 + lg * 4 + r;
        R2[h * 2048 + ((hd >> 3) * TOK + n) * 8 + (hd & 7)] = (_Float16)(acc[1][mt][r] + bq1);
      }
  }
  __syncthreads();  // b1: x reads done (R1 free), k visible

  // hoist kf; v^T -> R1 over x (acc[2] dies)
  f16x8 kf[4];
#pragma unroll
  for (int jt = 0; jt < 4; ++jt)
    kf[jt] = ld8(&R2[h * 2048 + (lg * TOK + jt * 16 + l15) * 8]);
  {
    float bq2 = b_qkv[2 * CDIM + sdl];
#pragma unroll
    for (int mt = 0; mt < 4; ++mt)
#pragma unroll
      for (int r = 0; r < 4; ++r) {
        int n = mt * 16 + lg * 4 + r;
        R1[h * 2048 + ((n >> 3) * HD + hd) * 8 + (n & 7)] = (_Float16)(acc[2][mt][r] + bq2);
      }
  }
  __syncthreads();  // b2: v^T visible, k dead (R2 region free)

  // hoist vf; q -> R2 over k (acc[0] dies)
  f16x8 vf[4];
#pragma unroll
  for (int z = 0; z < 4; ++z) {  // z = ks*2+nt
    int ks = z >> 1, nt = z & 1;
    vf[z] = ld8(&R1[h * 2048 + ((ks * 4 + lg) * HD + nt * 16 + l15) * 8]);
  }
  {
    float bq0 = b_qkv[sdl];
#pragma unroll
    for (int mt = 0; mt < 4; ++mt)
#pragma unroll
      for (int r = 0; r < 4; ++r) {
        int n = mt * 16 + lg * 4 + r;
        R2[h * 2048 + ((hd >> 3) * TOK + n) * 8 + (hd & 7)] =
            (_Float16)((acc[0][mt][r] + bq0) * QSCALE);
      }
  }
  __syncthreads();  // b3: q visible, v^T dead (R1 free for O)

  // hoist qf
  f16x8 qf[2];
#pragma unroll
  for (int ii = 0; ii < 2; ++ii) {
    int it = wh * 2 + ii;
    qf[ii] = ld8(&R2[h * 2048 + (lg * TOK + it * 16 + l15) * 8]);
  }
  __syncthreads();  // b4: q dead -> R2 free for P slices

  // ---------------- attention: 2 row-tiles per wave ----------------
  {
    _Float16* pbase = &R2[w * 1024];  // 2 KB P slice per wave
#pragma unroll
    for (int ii = 0; ii < 2; ++ii) {
      const int it = wh * 2 + ii;
      f32x4 st[4];
#pragma unroll
      for (int jt = 0; jt < 4; ++jt)
        st[jt] = __builtin_amdgcn_mfma_f32_16x16x32_f16(kf[jt], qf[ii], vzero, 0, 0, 0);
      // bias: lane holds (i = it*16+l15, j = jt*16+lg*4+r)
      if constexpr (WS) {
        const _Float16* bw = ws + BIAS_OFF + ((h * 4 + it) * 64 + l) * 16;
        f16x8 b0 = ld8(bw), b1 = ld8(bw + 8);
#pragma unroll
        for (int jt = 0; jt < 4; ++jt)
#pragma unroll
          for (int r = 0; r < 4; ++r)
            st[jt][r] += (float)((jt < 2) ? b0[jt * 4 + r] : b1[(jt - 2) * 4 + r]);
      } else {
        int i = it * 16 + l15, yi = i >> 3, xi = i & 7;
#pragma unroll
        for (int jt = 0; jt < 4; ++jt)
#pragma unroll
          for (int r = 0; r < 4; ++r) {
            int j = jt * 16 + lg * 4 + r, yj = j >> 3, xj = j & 7;
            st[jt][r] += bias_table[(((yi - yj + 7) * 15 + (xi - xj + 7)) * NH + h)];
          }
      }
      // softmax over row i: 16 in-lane + lanes differing in lg (xor 16,32)
      float m = st[0][0];
#pragma unroll
      for (int jt = 0; jt < 4; ++jt)
#pragma unroll
        for (int r = 0; r < 4; ++r) m = fmaxf(m, st[jt][r]);
      m = fmaxf(m, __shfl_xor(m, 16, 64));
      m = fmaxf(m, __shfl_xor(m, 32, 64));
      float sum = 0.f;
#pragma unroll
      for (int jt = 0; jt < 4; ++jt)
#pragma unroll
        for (int r = 0; r < 4; ++r) { st[jt][r] = __expf(st[jt][r] - m); sum += st[jt][r]; }
      sum += __shfl_xor(sum, 16, 64);
      sum += __shfl_xor(sum, 32, 64);
      float inv = 1.f / sum;
      // P slice write (packed f16x4), layout [j>>3][i16][j&7]
#pragma unroll
      for (int jt = 0; jt < 4; ++jt) {
        f16x4 pk;
#pragma unroll
        for (int r = 0; r < 4; ++r) pk[r] = (_Float16)(st[jt][r] * inv);
        *reinterpret_cast<f16x4*>(
            &pbase[((jt * 2 + (lg >> 1)) * 16 + l15) * 8 + (lg & 1) * 4]) = pk;
      }
      // PV: O[16x32] = P[16x64] @ V[64x32]
      f32x4 o[2] = {vzero, vzero};
#pragma unroll
      for (int ks = 0; ks < 2; ++ks) {
        f16x8 pf = ld8(&pbase[((ks * 4 + lg) * 16 + l15) * 8]);
#pragma unroll
        for (int nt = 0; nt < 2; ++nt)
          o[nt] = __builtin_amdgcn_mfma_f32_16x16x32_f16(pf, vf[ks * 2 + nt], o[nt], 0, 0, 0);
      }
      // O -> R1 flat panels [c>>3][i][c&7] (v^T globally dead since b3)
#pragma unroll
      for (int nt = 0; nt < 2; ++nt) {
        int c = h * HD + nt * 16 + l15;
#pragma unroll
        for (int r = 0; r < 4; ++r) {
          int i2 = it * 16 + lg * 4 + r;
          R1[((c >> 3) * TOK + i2) * 8 + (c & 7)] = (_Float16)o[nt][r];
        }
      }
    }
  }
  __syncthreads();  // b5: O visible

  // ------- projection (64x192, K=192); wave w -> e-tile w -------
  {
    const int e = w * 16 + l15;
    f32x4 pacc[4];
#pragma unroll
    for (int mt = 0; mt < 4; ++mt) pacc[mt] = vzero;
#pragma unroll
    for (int ks = 0; ks < 6; ++ks) {
      f16x8 bf;
      if constexpr (WS) bf = ld8(ws + WP16_OFF + (size_t)e * CDIM + ks * 32 + lg * 8);
      else              bf = cvt8(w_proj + (size_t)e * CDIM + ks * 32 + lg * 8);
#pragma unroll
      for (int mt = 0; mt < 4; ++mt) {
        f16x8 a = ld8(&R1[((ks * 4 + lg) * TOK + mt * 16 + l15) * 8]);
        pacc[mt] = __builtin_amdgcn_mfma_f32_16x16x32_f16(a, bf, pacc[mt], 0, 0, 0);
      }
    }
    float bp = b_proj[e];
#pragma unroll
    for (int mt = 0; mt < 4; ++mt)
#pragma unroll
      for (int r = 0; r < 4; ++r) {
        int n = mt * 16 + lg * 4 + r;
        out[((size_t)b * TOK + n) * CDIM + e] = pacc[mt][r] + bp;
      }
  }
}

extern "C" void kernel_launch(void* const* d_in, const int* in_sizes, int n_in,
                              void* d_out, int out_size, void* d_ws, size_t ws_size,
                              hipStream_t stream) {
  const float* x          = (const float*)d_in[0];
  const float* w_qkv      = (const float*)d_in[1];
  const float* b_qkv      = (const float*)d_in[2];
  const float* w_proj     = (const float*)d_in[3];
  const float* b_proj     = (const float*)d_in[4];
  const float* bias_table = (const float*)d_in[5];
  float* out = (float*)d_out;
  int B = in_sizes[0] / (TOK * CDIM);

  if (ws_size >= (size_t)WS_BYTES) {
    _Float16* ws = (_Float16*)d_ws;
    hipLaunchKernelGGL(prep_ws, dim3(240), dim3(256), 0, stream,
                       w_qkv, w_proj, bias_table, ws);
    hipLaunchKernelGGL(winattn<true>, dim3(B), dim3(THREADS), 0, stream,
                       x, w_qkv, b_qkv, w_proj, b_proj, bias_table, ws, out);
  } else {
    hipLaunchKernelGGL(winattn<false>, dim3(B), dim3(THREADS), 0, stream,
                       x, w_qkv, b_qkv, w_proj, b_proj, bias_table,
                       (const _Float16*)nullptr, out);
  }
}

// Round 6
// 213.640 us; speedup vs baseline: 1.7073x; 1.3766x over previous
//
#include <hip/hip_runtime.h>

#define TOK 64
#define CDIM 192
#define NH 6
#define HD 32
#define THREADS 768
#define QSCALE 0.17677669529663687f  // 32^-0.5

// workspace layout (halfs): w_qkv16 [576*192] | w_proj16 [192*192] | bias frags [6*4*64*16]
#define WQ16_OFF 0
#define WP16_OFF 110592
#define BIAS_OFF 147456
#define WS_HALFS (147456 + 24576)
#define WS_BYTES (WS_HALFS * 2)

typedef _Float16 f16x8 __attribute__((ext_vector_type(8)));
typedef _Float16 f16x4 __attribute__((ext_vector_type(4)));
typedef float f32x4 __attribute__((ext_vector_type(4)));

__device__ __forceinline__ f16x8 ld8(const _Float16* p) {
  return *reinterpret_cast<const f16x8*>(p);
}

__device__ __forceinline__ f16x8 cvt8(const float* __restrict__ p) {
  float4 a = *reinterpret_cast<const float4*>(p);
  float4 c = *reinterpret_cast<const float4*>(p + 4);
  f16x8 r;
  r[0] = (_Float16)a.x; r[1] = (_Float16)a.y; r[2] = (_Float16)a.z; r[3] = (_Float16)a.w;
  r[4] = (_Float16)c.x; r[5] = (_Float16)c.y; r[6] = (_Float16)c.z; r[7] = (_Float16)c.w;
  return r;
}

// Prologue: fp16 weights + per-(head,row-tile) bias fragments (two f16x8 per lane).
__global__ void prep_ws(const float* __restrict__ wq, const float* __restrict__ wp,
                        const float* __restrict__ bt, _Float16* __restrict__ ws) {
  int i = blockIdx.x * 256 + threadIdx.x;
  if (i < 27648) {
    float4 v = reinterpret_cast<const float4*>(wq)[i];
    f16x4 h;
    h[0] = (_Float16)v.x; h[1] = (_Float16)v.y; h[2] = (_Float16)v.z; h[3] = (_Float16)v.w;
    *reinterpret_cast<f16x4*>(ws + WQ16_OFF + (size_t)i * 4) = h;
  } else if (i < 36864) {
    int j = i - 27648;
    float4 v = reinterpret_cast<const float4*>(wp)[j];
    f16x4 h;
    h[0] = (_Float16)v.x; h[1] = (_Float16)v.y; h[2] = (_Float16)v.z; h[3] = (_Float16)v.w;
    *reinterpret_cast<f16x4*>(ws + WP16_OFF + (size_t)j * 4) = h;
  } else if (i < 61440) {
    int j = i - 36864;            // ((h*4+it)*64 + lane)*16 + (jt*4+r)
    int hit = j >> 10;
    int l = (j >> 4) & 63;
    int s = j & 15;
    int h = hit >> 2, it = hit & 3;
    int ii = it * 16 + (l & 15);
    int jj = (s >> 2) * 16 + (l >> 4) * 4 + (s & 3);
    int rel = ((ii >> 3) - (jj >> 3) + 7) * 15 + ((ii & 7) - (jj & 7) + 7);
    ws[BIAS_OFF + j] = (_Float16)bt[rel * NH + h];
  }
}

// Fused window attention: 1 block = 1 window, 12 waves, 48 KB LDS -> 2 blocks/CU.
// Spill-free under the 85-reg/wave budget of __launch_bounds__(768,6) by
// splitting QKV into two passes over the resident x panels:
//   pass A: q+k (32 acc)  -> k stored, dies;  pass B: v (16 acc), q still live.
// Peak live set ~66 regs (was ~88 -> inner-loop spill in rounds 4/5).
// Overlay chains: R1: x -> v^T -> O      R2: k -> q -> P slices
// Panel layout: elem(row,k) at [(k>>3)*ROWS + row]*8 + (k&7): all MFMA
// fragment accesses are contiguous 16B ds_read_b128.
template <bool WS>
__global__ __launch_bounds__(THREADS, 6) void winattn(
    const float* __restrict__ x, const float* __restrict__ w_qkv,
    const float* __restrict__ b_qkv, const float* __restrict__ w_proj,
    const float* __restrict__ b_proj, const float* __restrict__ bias_table,
    const _Float16* __restrict__ ws, float* __restrict__ out) {
  __shared__ __align__(16) _Float16 R1[12288];  // x -> v^T -> O
  __shared__ __align__(16) _Float16 R2[12288];  // k -> q -> P

  const int tid = threadIdx.x;
  const int w   = tid >> 6;   // 0..11
  const int l   = tid & 63;
  const int l15 = l & 15;
  const int lg  = l >> 4;
  const int b   = blockIdx.x;
  const int h   = w >> 1;     // head
  const int wh  = w & 1;      // half (dims in QKV, rows in attention)
  const f32x4 vzero = {0.f, 0.f, 0.f, 0.f};

  // ---------------- stage x (fp32 -> fp16 panels) ----------------
  const float* xg = x + (size_t)b * (TOK * CDIM);
#pragma unroll
  for (int i = tid; i < TOK * CDIM / 4; i += THREADS) {
    int n = i / (CDIM / 4);
    int c = (i % (CDIM / 4)) * 4;
    float4 v = reinterpret_cast<const float4*>(xg)[i];
    f16x4 h4;
    h4[0] = (_Float16)v.x; h4[1] = (_Float16)v.y;
    h4[2] = (_Float16)v.z; h4[3] = (_Float16)v.w;
    *reinterpret_cast<f16x4*>(&R1[((c >> 3) * TOK + n) * 8 + (c & 7)]) = h4;
  }
  __syncthreads();  // b0

  const int sdl = h * HD + wh * 16 + l15;  // out-dim within each part
  const int hd  = wh * 16 + l15;           // dim within head

  // ------- QKV pass A: q + k (K=192) -------
  f32x4 aq[4], ak[4];
#pragma unroll
  for (int mt = 0; mt < 4; ++mt) { aq[mt] = vzero; ak[mt] = vzero; }
#pragma unroll
  for (int ks = 0; ks < 6; ++ks) {
    f16x8 a[4];
#pragma unroll
    for (int mt = 0; mt < 4; ++mt)
      a[mt] = ld8(&R1[((ks * 4 + lg) * TOK + mt * 16 + l15) * 8]);
    f16x8 bfq, bfk;
    if constexpr (WS) {
      bfq = ld8(ws + WQ16_OFF + (size_t)sdl * CDIM + ks * 32 + lg * 8);
      bfk = ld8(ws + WQ16_OFF + (size_t)(CDIM + sdl) * CDIM + ks * 32 + lg * 8);
    } else {
      bfq = cvt8(w_qkv + (size_t)sdl * CDIM + ks * 32 + lg * 8);
      bfk = cvt8(w_qkv + (size_t)(CDIM + sdl) * CDIM + ks * 32 + lg * 8);
    }
#pragma unroll
    for (int mt = 0; mt < 4; ++mt) {
      aq[mt] = __builtin_amdgcn_mfma_f32_16x16x32_f16(a[mt], bfq, aq[mt], 0, 0, 0);
      ak[mt] = __builtin_amdgcn_mfma_f32_16x16x32_f16(a[mt], bfk, ak[mt], 0, 0, 0);
    }
  }
  // k -> R2 (ak dies)
  {
    float bq1 = b_qkv[CDIM + sdl];
#pragma unroll
    for (int mt = 0; mt < 4; ++mt)
#pragma unroll
      for (int r = 0; r < 4; ++r) {
        int n = mt * 16 + lg * 4 + r;
        R2[h * 2048 + ((hd >> 3) * TOK + n) * 8 + (hd & 7)] = (_Float16)(ak[mt][r] + bq1);
      }
  }

  // ------- QKV pass B: v (x panels still resident) -------
  f32x4 av[4];
#pragma unroll
  for (int mt = 0; mt < 4; ++mt) av[mt] = vzero;
#pragma unroll
  for (int ks = 0; ks < 6; ++ks) {
    f16x8 a[4];
#pragma unroll
    for (int mt = 0; mt < 4; ++mt)
      a[mt] = ld8(&R1[((ks * 4 + lg) * TOK + mt * 16 + l15) * 8]);
    f16x8 bfv;
    if constexpr (WS) bfv = ld8(ws + WQ16_OFF + (size_t)(2 * CDIM + sdl) * CDIM + ks * 32 + lg * 8);
    else              bfv = cvt8(w_qkv + (size_t)(2 * CDIM + sdl) * CDIM + ks * 32 + lg * 8);
#pragma unroll
    for (int mt = 0; mt < 4; ++mt)
      av[mt] = __builtin_amdgcn_mfma_f32_16x16x32_f16(a[mt], bfv, av[mt], 0, 0, 0);
  }
  __syncthreads();  // b1: x reads done (R1 free), k visible

  // hoist kf; v^T -> R1 over x (av dies)
  f16x8 kf[4];
#pragma unroll
  for (int jt = 0; jt < 4; ++jt)
    kf[jt] = ld8(&R2[h * 2048 + (lg * TOK + jt * 16 + l15) * 8]);
  {
    float bq2 = b_qkv[2 * CDIM + sdl];
#pragma unroll
    for (int mt = 0; mt < 4; ++mt)
#pragma unroll
      for (int r = 0; r < 4; ++r) {
        int n = mt * 16 + lg * 4 + r;
        R1[h * 2048 + ((n >> 3) * HD + hd) * 8 + (n & 7)] = (_Float16)(av[mt][r] + bq2);
      }
  }
  __syncthreads();  // b2: v^T visible, k dead (R2 region free)

  // hoist vf; q -> R2 over k (aq dies)
  f16x8 vf[4];
#pragma unroll
  for (int z = 0; z < 4; ++z) {  // z = ks*2+nt
    int ks = z >> 1, nt = z & 1;
    vf[z] = ld8(&R1[h * 2048 + ((ks * 4 + lg) * HD + nt * 16 + l15) * 8]);
  }
  {
    float bq0 = b_qkv[sdl];
#pragma unroll
    for (int mt = 0; mt < 4; ++mt)
#pragma unroll
      for (int r = 0; r < 4; ++r) {
        int n = mt * 16 + lg * 4 + r;
        R2[h * 2048 + ((hd >> 3) * TOK + n) * 8 + (hd & 7)] =
            (_Float16)((aq[mt][r] + bq0) * QSCALE);
      }
  }
  __syncthreads();  // b3: q visible, v^T dead (R1 free for O)

  // hoist qf
  f16x8 qf[2];
#pragma unroll
  for (int ii = 0; ii < 2; ++ii) {
    int it = wh * 2 + ii;
    qf[ii] = ld8(&R2[h * 2048 + (lg * TOK + it * 16 + l15) * 8]);
  }
  __syncthreads();  // b4: q dead -> R2 free for P slices

  // ---------------- attention: 2 row-tiles per wave ----------------
  {
    _Float16* pbase = &R2[w * 1024];  // 2 KB P slice per wave
#pragma unroll
    for (int ii = 0; ii < 2; ++ii) {
      const int it = wh * 2 + ii;
      f32x4 st[4];
#pragma unroll
      for (int jt = 0; jt < 4; ++jt)
        st[jt] = __builtin_amdgcn_mfma_f32_16x16x32_f16(kf[jt], qf[ii], vzero, 0, 0, 0);
      // bias: lane holds (i = it*16+l15, j = jt*16+lg*4+r)
      if constexpr (WS) {
        const _Float16* bw = ws + BIAS_OFF + ((h * 4 + it) * 64 + l) * 16;
        f16x8 b0 = ld8(bw), b1 = ld8(bw + 8);
#pragma unroll
        for (int jt = 0; jt < 4; ++jt)
#pragma unroll
          for (int r = 0; r < 4; ++r)
            st[jt][r] += (float)((jt < 2) ? b0[jt * 4 + r] : b1[(jt - 2) * 4 + r]);
      } else {
        int i = it * 16 + l15, yi = i >> 3, xi = i & 7;
#pragma unroll
        for (int jt = 0; jt < 4; ++jt)
#pragma unroll
          for (int r = 0; r < 4; ++r) {
            int j = jt * 16 + lg * 4 + r, yj = j >> 3, xj = j & 7;
            st[jt][r] += bias_table[(((yi - yj + 7) * 15 + (xi - xj + 7)) * NH + h)];
          }
      }
      // softmax over row i: 16 in-lane + lanes differing in lg (xor 16,32)
      float m = st[0][0];
#pragma unroll
      for (int jt = 0; jt < 4; ++jt)
#pragma unroll
        for (int r = 0; r < 4; ++r) m = fmaxf(m, st[jt][r]);
      m = fmaxf(m, __shfl_xor(m, 16, 64));
      m = fmaxf(m, __shfl_xor(m, 32, 64));
      float sum = 0.f;
#pragma unroll
      for (int jt = 0; jt < 4; ++jt)
#pragma unroll
        for (int r = 0; r < 4; ++r) { st[jt][r] = __expf(st[jt][r] - m); sum += st[jt][r]; }
      sum += __shfl_xor(sum, 16, 64);
      sum += __shfl_xor(sum, 32, 64);
      float inv = 1.f / sum;
      // P slice write (packed f16x4), layout [j>>3][i16][j&7]
#pragma unroll
      for (int jt = 0; jt < 4; ++jt) {
        f16x4 pk;
#pragma unroll
        for (int r = 0; r < 4; ++r) pk[r] = (_Float16)(st[jt][r] * inv);
        *reinterpret_cast<f16x4*>(
            &pbase[((jt * 2 + (lg >> 1)) * 16 + l15) * 8 + (lg & 1) * 4]) = pk;
      }
      // PV: O[16x32] = P[16x64] @ V[64x32]
      f32x4 o[2] = {vzero, vzero};
#pragma unroll
      for (int ks = 0; ks < 2; ++ks) {
        f16x8 pf = ld8(&pbase[((ks * 4 + lg) * 16 + l15) * 8]);
#pragma unroll
        for (int nt = 0; nt < 2; ++nt)
          o[nt] = __builtin_amdgcn_mfma_f32_16x16x32_f16(pf, vf[ks * 2 + nt], o[nt], 0, 0, 0);
      }
      // O -> R1 flat panels [c>>3][i][c&7] (v^T globally dead since b3)
#pragma unroll
      for (int nt = 0; nt < 2; ++nt) {
        int c = h * HD + nt * 16 + l15;
#pragma unroll
        for (int r = 0; r < 4; ++r) {
          int i2 = it * 16 + lg * 4 + r;
          R1[((c >> 3) * TOK + i2) * 8 + (c & 7)] = (_Float16)o[nt][r];
        }
      }
    }
  }
  __syncthreads();  // b5: O visible

  // ------- projection (64x192, K=192); wave w -> e-tile w -------
  {
    const int e = w * 16 + l15;
    f32x4 pacc[4];
#pragma unroll
    for (int mt = 0; mt < 4; ++mt) pacc[mt] = vzero;
#pragma unroll
    for (int ks = 0; ks < 6; ++ks) {
      f16x8 bf;
      if constexpr (WS) bf = ld8(ws + WP16_OFF + (size_t)e * CDIM + ks * 32 + lg * 8);
      else              bf = cvt8(w_proj + (size_t)e * CDIM + ks * 32 + lg * 8);
#pragma unroll
      for (int mt = 0; mt < 4; ++mt) {
        f16x8 a = ld8(&R1[((ks * 4 + lg) * TOK + mt * 16 + l15) * 8]);
        pacc[mt] = __builtin_amdgcn_mfma_f32_16x16x32_f16(a, bf, pacc[mt], 0, 0, 0);
      }
    }
    float bp = b_proj[e];
#pragma unroll
    for (int mt = 0; mt < 4; ++mt)
#pragma unroll
      for (int r = 0; r < 4; ++r) {
        int n = mt * 16 + lg * 4 + r;
        out[((size_t)b * TOK + n) * CDIM + e] = pacc[mt][r] + bp;
      }
  }
}

extern "C" void kernel_launch(void* const* d_in, const int* in_sizes, int n_in,
                              void* d_out, int out_size, void* d_ws, size_t ws_size,
                              hipStream_t stream) {
  const float* x          = (const float*)d_in[0];
  const float* w_qkv      = (const float*)d_in[1];
  const float* b_qkv      = (const float*)d_in[2];
  const float* w_proj     = (const float*)d_in[3];
  const float* b_proj     = (const float*)d_in[4];
  const float* bias_table = (const float*)d_in[5];
  float* out = (float*)d_out;
  int B = in_sizes[0] / (TOK * CDIM);

  if (ws_size >= (size_t)WS_BYTES) {
    _Float16* ws = (_Float16*)d_ws;
    hipLaunchKernelGGL(prep_ws, dim3(240), dim3(256), 0, stream,
                       w_qkv, w_proj, bias_table, ws);
    hipLaunchKernelGGL(winattn<true>, dim3(B), dim3(THREADS), 0, stream,
                       x, w_qkv, b_qkv, w_proj, b_proj, bias_table, ws, out);
  } else {
    hipLaunchKernelGGL(winattn<false>, dim3(B), dim3(THREADS), 0, stream,
                       x, w_qkv, b_qkv, w_proj, b_proj, bias_table,
                       (const _Float16*)nullptr, out);
  }
}